// Round 3
// baseline (454.966 us; speedup 1.0000x reference)
//
#include <hip/hip_runtime.h>

#define F 128      // IN_FEATS == HEADS*HID == 128 (both layers)
#define HEADS 4
#define HID 32

// RNE float -> bf16 bits
static __device__ __forceinline__ unsigned short f2bf(float f) {
  unsigned u = __float_as_uint(f);
  unsigned r = (u + 0x7fffu + ((u >> 16) & 1u)) >> 16;
  return (unsigned short)r;
}

// ---------------- CSR build (by dst) ----------------
__global__ void hist_k(const int* __restrict__ dst, int* __restrict__ deg, int E) {
  int i = blockIdx.x * blockDim.x + threadIdx.x;
  if (i < E) atomicAdd(&deg[dst[i]], 1);
}

__global__ void block_sum_k(const int* __restrict__ deg, int* __restrict__ bsum, int N) {
  __shared__ int sh[256];
  int t = threadIdx.x;
  int base = blockIdx.x * 1024 + t * 4;
  int s = 0;
#pragma unroll
  for (int m = 0; m < 4; ++m) { int idx = base + m; if (idx < N) s += deg[idx]; }
  sh[t] = s; __syncthreads();
  for (int off = 128; off > 0; off >>= 1) {
    if (t < off) sh[t] += sh[t + off];
    __syncthreads();
  }
  if (t == 0) bsum[blockIdx.x] = sh[0];
}

// exclusive scan of nb<=64 block sums, one wave
__global__ void scan_small_k(int* bsum, int nb) {
  int t = threadIdx.x;
  int v = (t < nb) ? bsum[t] : 0;
  int orig = v;
  for (int off = 1; off < 64; off <<= 1) {
    int u = __shfl_up(v, off);
    if (t >= off) v += u;
  }
  if (t < nb) bsum[t] = v - orig;  // exclusive
}

// exclusive scan of deg -> rp; also writes cursor copy (in-place into deg)
__global__ void scan_final_k(int* __restrict__ deg, const int* __restrict__ bsum,
                             int* __restrict__ rp, int N, int E) {
  __shared__ int sh[256];
  int t = threadIdx.x, b = blockIdx.x;
  int base = b * 1024 + t * 4;
  int v[4]; int ts = 0;
#pragma unroll
  for (int m = 0; m < 4; ++m) { v[m] = (base + m < N) ? deg[base + m] : 0; ts += v[m]; }
  sh[t] = ts; __syncthreads();
  for (int off = 1; off < 256; off <<= 1) {
    int x = (t >= off) ? sh[t - off] : 0;
    __syncthreads();
    sh[t] += x;
    __syncthreads();
  }
  int p = bsum[b] + sh[t] - ts;
#pragma unroll
  for (int m = 0; m < 4; ++m) {
    int idx = base + m;
    if (idx < N) { rp[idx] = p; deg[idx] = p; }
    p += v[m];
  }
  if (b == 0 && t == 0) rp[N] = E;
}

__global__ void scatter_k(const int* __restrict__ src, const int* __restrict__ dst,
                          int* __restrict__ cursor, int* __restrict__ csr_src, int E) {
  int i = blockIdx.x * blockDim.x + threadIdx.x;
  if (i < E) {
    int pos = atomicAdd(&cursor[dst[i]], 1);
    csr_src[pos] = src[i];
  }
}

// ---------------- fused GEMM + attention logits + bf16 head-plane pack -------
// H[N,128] = X[N,128] @ W[128,128] (fp32 accum). Epilogue:
//   hbp[hd][n][32] <- bf16(H)      (head-major planes: 3.2 MB each, L2-resident)
//   elp[hd][n], erp[hd][n]         (fp32 head-major logit planes)
__global__ __launch_bounds__(256) void gemm_fused_k(const float* __restrict__ X,
                                                    const float* __restrict__ W,
                                                    const float* __restrict__ alf,
                                                    const float* __restrict__ arf,
                                                    unsigned short* __restrict__ hbp,
                                                    float* __restrict__ elp,
                                                    float* __restrict__ erp, int N) {
  __shared__ float xs[64 * 132];   // +4 pad: float4-aligned, breaks bank stride
  __shared__ float ws[32 * 128];
  int tid = threadIdx.x;
  int n0 = blockIdx.x * 64;

  // load X tile (64x128)
#pragma unroll
  for (int j = 0; j < 8; ++j) {
    int idx4 = tid + j * 256;
    int r = idx4 >> 5;
    int c4 = idx4 & 31;
    float4 v = make_float4(0.f, 0.f, 0.f, 0.f);
    if (n0 + r < N) v = *(const float4*)&X[(long)(n0 + r) * F + c4 * 4];
    *(float4*)&xs[r * 132 + c4 * 4] = v;
  }

  int ng = tid >> 4;   // rows 4*ng..4*ng+3
  int cg = tid & 15;   // cols 8*cg..8*cg+7 (all within head cg>>2)
  float acc[4][8];
#pragma unroll
  for (int i = 0; i < 4; ++i)
#pragma unroll
    for (int j = 0; j < 8; ++j) acc[i][j] = 0.f;

  for (int kk = 0; kk < 4; ++kk) {
    __syncthreads();
#pragma unroll
    for (int j = 0; j < 4; ++j) {
      int idx4 = tid + j * 256;
      int r = idx4 >> 5;
      int c4 = idx4 & 31;
      *(float4*)&ws[r * 128 + c4 * 4] = *(const float4*)&W[(kk * 32 + r) * F + c4 * 4];
    }
    __syncthreads();
#pragma unroll
    for (int k = 0; k < 32; ++k) {
      float xv[4];
#pragma unroll
      for (int i = 0; i < 4; ++i) xv[i] = xs[(4 * ng + i) * 132 + kk * 32 + k];
      float4 w0 = *(float4*)&ws[k * 128 + cg * 8];
      float4 w1 = *(float4*)&ws[k * 128 + cg * 8 + 4];
      float wv[8] = {w0.x, w0.y, w0.z, w0.w, w1.x, w1.y, w1.z, w1.w};
#pragma unroll
      for (int i = 0; i < 4; ++i)
#pragma unroll
        for (int j = 0; j < 8; ++j) acc[i][j] += xv[i] * wv[j];
    }
  }

  // --- epilogue 1: bf16 pack + store into head plane ---
  int hd = cg >> 2;               // this thread's head
  int foff = (cg & 3) * 8;        // in-head feature offset
#pragma unroll
  for (int i = 0; i < 4; ++i) {
    int r = n0 + 4 * ng + i;
    if (r < N) {
      uint4 pk;
      pk.x = (unsigned)f2bf(acc[i][0]) | ((unsigned)f2bf(acc[i][1]) << 16);
      pk.y = (unsigned)f2bf(acc[i][2]) | ((unsigned)f2bf(acc[i][3]) << 16);
      pk.z = (unsigned)f2bf(acc[i][4]) | ((unsigned)f2bf(acc[i][5]) << 16);
      pk.w = (unsigned)f2bf(acc[i][6]) | ((unsigned)f2bf(acc[i][7]) << 16);
      *(uint4*)&hbp[(size_t)hd * N * HID + (long)r * HID + foff] = pk;
    }
  }

  // --- epilogue 2: el/er via 4-lane shfl_xor reduce ---
  float pl[4], pr[4];
#pragma unroll
  for (int i = 0; i < 4; ++i) { pl[i] = 0.f; pr[i] = 0.f; }
#pragma unroll
  for (int j = 0; j < 8; ++j) {
    float a = alf[cg * 8 + j];
    float b = arf[cg * 8 + j];
#pragma unroll
    for (int i = 0; i < 4; ++i) { pl[i] += acc[i][j] * a; pr[i] += acc[i][j] * b; }
  }
#pragma unroll
  for (int i = 0; i < 4; ++i) {
    pl[i] += __shfl_xor(pl[i], 1); pl[i] += __shfl_xor(pl[i], 2);
    pr[i] += __shfl_xor(pr[i], 1); pr[i] += __shfl_xor(pr[i], 2);
  }
  if ((cg & 3) == 0) {
#pragma unroll
    for (int i = 0; i < 4; ++i) {
      int r = n0 + 4 * ng + i;
      if (r < N) { elp[(size_t)hd * N + r] = pl[i]; erp[(size_t)hd * N + r] = pr[i]; }
    }
  }
}

// ---------------- fused edge-softmax + aggregation + bias + ELU ----------------
// Head-split: one wave per (dst node, head). blockIdx = chunk*4 + head, so
// round-robin block->XCD dispatch pins head h to XCDs {h, h+4}; that XCD's L2
// then holds exactly one 3.2 MB hbp plane + 200 KB elp plane (fits 4 MB).
// Lanes 0-31 process even edges, 32-63 odd edges (2 edges/step, feature=lane&31).
// Weights exp(lrelu(el+er)) computed 64-wide in the batch prologue (latency
// off the serial chain); serial body is 2 shfl + 1 gather + 2 FMA, 2-step unrolled.
__global__ __launch_bounds__(256) void agg_k(const int* __restrict__ rp,
                                             const int* __restrict__ csr_src,
                                             const float* __restrict__ elp,
                                             const float* __restrict__ erp,
                                             const unsigned short* __restrict__ hbp,
                                             const float* __restrict__ bias,
                                             float* __restrict__ out, int N) {
  int hd = blockIdx.x & 3;
  int chunk = blockIdx.x >> 2;
  int d = chunk * 4 + (threadIdx.x >> 6);
  int lane = threadIdx.x & 63;
  if (d >= N) return;
  int f = lane & 31;
  int half = lane >> 5;
  const unsigned short* hplane = hbp + (size_t)hd * N * HID;
  const float* eplane = elp + (size_t)hd * N;
  float erd = erp[(size_t)hd * N + d];
  int i0 = rp[d], i1 = rp[d + 1];

  float acc0 = 0.f, acc1 = 0.f, asum0 = 0.f, asum1 = 0.f;
  for (int base = i0; base < i1; base += 64) {
    int cnt = i1 - base; if (cnt > 64) cnt = 64;
    int sv = 0; float wv = 0.f;
    if (lane < cnt) {
      sv = __builtin_nontemporal_load(&csr_src[base + lane]);   // coalesced, read-once
      float e = eplane[sv] + erd;          // 64-wide parallel gather (L2-resident plane)
      e = e > 0.f ? e : 0.2f * e;          // LeakyReLU(0.2)
      wv = __expf(e);                      // max-subtraction provably unneeded (e~N(0,2))
    }
    int j = 0;
    for (; j + 4 <= cnt; j += 4) {         // 4 edges in flight (2 halves x 2-unroll)
      int ia = j + half, ib = j + 2 + half;
      int s0 = __shfl(sv, ia), s1 = __shfl(sv, ib);
      float w0 = __shfl(wv, ia), w1 = __shfl(wv, ib);
      unsigned short h0 = hplane[(size_t)s0 * HID + f];
      unsigned short h1 = hplane[(size_t)s1 * HID + f];
      acc0 += w0 * __uint_as_float(((unsigned)h0) << 16);
      acc1 += w1 * __uint_as_float(((unsigned)h1) << 16);
      asum0 += w0; asum1 += w1;
    }
    for (; j < cnt; j += 2) {              // tail (<=3 edges)
      int ia = j + half;
      int s0 = __shfl(sv, ia);
      float w0 = __shfl(wv, ia);
      if (ia >= cnt) w0 = 0.f;
      unsigned short h0 = hplane[(size_t)s0 * HID + f];
      acc0 += w0 * __uint_as_float(((unsigned)h0) << 16);
      asum0 += w0;
    }
  }
  float acc = acc0 + acc1, asum = asum0 + asum1;
  acc += __shfl_xor(acc, 32);              // combine even/odd halves
  asum += __shfl_xor(asum, 32);
  if (half == 0) {
    float inv = 1.f / fmaxf(asum, 1e-9f);
    float o = acc * inv + bias[hd * HID + f];
    o = o > 0.f ? o : (__expf(o) - 1.f);   // ELU
    out[(size_t)d * F + hd * HID + f] = o;
  }
}

extern "C" void kernel_launch(void* const* d_in, const int* in_sizes, int n_in,
                              void* d_out, int out_size, void* d_ws, size_t ws_size,
                              hipStream_t stream) {
  const float* feat = (const float*)d_in[0];
  const int*   src  = (const int*)d_in[1];
  const int*   dst  = (const int*)d_in[2];
  const float* W1   = (const float*)d_in[3];
  const float* al1  = (const float*)d_in[4];
  const float* ar1  = (const float*)d_in[5];
  const float* b1   = (const float*)d_in[6];
  const float* W2   = (const float*)d_in[7];
  const float* al2  = (const float*)d_in[8];
  const float* ar2  = (const float*)d_in[9];
  const float* b2   = (const float*)d_in[10];
  float* out = (float*)d_out;
  int N = in_sizes[0] / F;
  int E = in_sizes[1];

  // workspace layout (~18 MB)
  char* ws = (char*)d_ws;
  auto align256 = [](size_t x) { return (x + 255) & ~(size_t)255; };
  int* rp      = (int*)ws; ws += align256((size_t)(N + 1) * 4);
  int* deg     = (int*)ws; ws += align256((size_t)N * 4);        // becomes cursor
  int* bsum    = (int*)ws; ws += 1024;
  int* csr_src = (int*)ws; ws += align256((size_t)E * 4);
  float* elp   = (float*)ws; ws += align256((size_t)N * HEADS * 4);
  float* erp   = (float*)ws; ws += align256((size_t)N * HEADS * 4);
  unsigned short* hbp = (unsigned short*)ws; ws += align256((size_t)N * F * 2);

  int nbScan = (N + 1023) / 1024;   // 49 <= 64

  // CSR build (graph static but ws is re-poisoned every call — rebuild)
  hipMemsetAsync(deg, 0, (size_t)N * 4, stream);
  hist_k<<<(E + 255) / 256, 256, 0, stream>>>(dst, deg, E);
  block_sum_k<<<nbScan, 256, 0, stream>>>(deg, bsum, N);
  scan_small_k<<<1, 64, 0, stream>>>(bsum, nbScan);
  scan_final_k<<<nbScan, 256, 0, stream>>>(deg, bsum, rp, N, E);
  scatter_k<<<(E + 255) / 256, 256, 0, stream>>>(src, dst, deg, csr_src, E);

  int gemmBlocks = (N + 63) / 64;
  int aggBlocks  = ((N + 3) / 4) * 4;   // chunk*4 + head

  // layer 1: out <- elu(GAT(feat))
  gemm_fused_k<<<gemmBlocks, 256, 0, stream>>>(feat, W1, al1, ar1, hbp, elp, erp, N);
  agg_k<<<aggBlocks, 256, 0, stream>>>(rp, csr_src, elp, erp, hbp, b1, out, N);

  // layer 2: out <- elu(GAT(out))
  gemm_fused_k<<<gemmBlocks, 256, 0, stream>>>(out, W2, al2, ar2, hbp, elp, erp, N);
  agg_k<<<aggBlocks, 256, 0, stream>>>(rp, csr_src, elp, erp, hbp, b2, out, N);
}

// Round 4
// 357.741 us; speedup vs baseline: 1.2718x; 1.2718x over previous
//
#include <hip/hip_runtime.h>

#define F 128      // IN_FEATS == HEADS*HID == 128 (both layers)
#define HEADS 4
#define HID 32

// RNE float -> bf16 bits
static __device__ __forceinline__ unsigned short f2bf(float f) {
  unsigned u = __float_as_uint(f);
  unsigned r = (u + 0x7fffu + ((u >> 16) & 1u)) >> 16;
  return (unsigned short)r;
}

// ---------------- CSR build (by dst) ----------------
__global__ void hist_k(const int* __restrict__ dst, int* __restrict__ deg, int E) {
  int i = blockIdx.x * blockDim.x + threadIdx.x;
  if (i < E) atomicAdd(&deg[dst[i]], 1);
}

__global__ void block_sum_k(const int* __restrict__ deg, int* __restrict__ bsum, int N) {
  __shared__ int sh[256];
  int t = threadIdx.x;
  int base = blockIdx.x * 1024 + t * 4;
  int s = 0;
#pragma unroll
  for (int m = 0; m < 4; ++m) { int idx = base + m; if (idx < N) s += deg[idx]; }
  sh[t] = s; __syncthreads();
  for (int off = 128; off > 0; off >>= 1) {
    if (t < off) sh[t] += sh[t + off];
    __syncthreads();
  }
  if (t == 0) bsum[blockIdx.x] = sh[0];
}

// exclusive scan of nb<=64 block sums, one wave
__global__ void scan_small_k(int* bsum, int nb) {
  int t = threadIdx.x;
  int v = (t < nb) ? bsum[t] : 0;
  int orig = v;
  for (int off = 1; off < 64; off <<= 1) {
    int u = __shfl_up(v, off);
    if (t >= off) v += u;
  }
  if (t < nb) bsum[t] = v - orig;  // exclusive
}

// exclusive scan of deg -> rp; also writes cursor copy (in-place into deg)
__global__ void scan_final_k(int* __restrict__ deg, const int* __restrict__ bsum,
                             int* __restrict__ rp, int N, int E) {
  __shared__ int sh[256];
  int t = threadIdx.x, b = blockIdx.x;
  int base = b * 1024 + t * 4;
  int v[4]; int ts = 0;
#pragma unroll
  for (int m = 0; m < 4; ++m) { v[m] = (base + m < N) ? deg[base + m] : 0; ts += v[m]; }
  sh[t] = ts; __syncthreads();
  for (int off = 1; off < 256; off <<= 1) {
    int x = (t >= off) ? sh[t - off] : 0;
    __syncthreads();
    sh[t] += x;
    __syncthreads();
  }
  int p = bsum[b] + sh[t] - ts;
#pragma unroll
  for (int m = 0; m < 4; ++m) {
    int idx = base + m;
    if (idx < N) { rp[idx] = p; deg[idx] = p; }
    p += v[m];
  }
  if (b == 0 && t == 0) rp[N] = E;
}

__global__ void scatter_k(const int* __restrict__ src, const int* __restrict__ dst,
                          int* __restrict__ cursor, int* __restrict__ csr_src, int E) {
  int i = blockIdx.x * blockDim.x + threadIdx.x;
  if (i < E) {
    int pos = atomicAdd(&cursor[dst[i]], 1);
    csr_src[pos] = src[i];
  }
}

// ---------------- fused GEMM + attention logits + bf16 pack (node-major) -----
// H[N,128] = X[N,128] @ W[128,128] (fp32 accum). Epilogue:
//   hb[n][128] <- bf16(H); el[n][4], er[n][4] (fp32). fp32 H never materialized.
__global__ __launch_bounds__(256) void gemm_fused_k(const float* __restrict__ X,
                                                    const float* __restrict__ W,
                                                    const float* __restrict__ alf,
                                                    const float* __restrict__ arf,
                                                    unsigned short* __restrict__ hb,
                                                    float* __restrict__ el,
                                                    float* __restrict__ er, int N) {
  __shared__ float xs[64 * 132];   // +4 pad: float4-aligned, breaks bank stride
  __shared__ float ws[32 * 128];
  int tid = threadIdx.x;
  int n0 = blockIdx.x * 64;

  // load X tile (64x128)
#pragma unroll
  for (int j = 0; j < 8; ++j) {
    int idx4 = tid + j * 256;
    int r = idx4 >> 5;
    int c4 = idx4 & 31;
    float4 v = make_float4(0.f, 0.f, 0.f, 0.f);
    if (n0 + r < N) v = *(const float4*)&X[(long)(n0 + r) * F + c4 * 4];
    *(float4*)&xs[r * 132 + c4 * 4] = v;
  }

  int ng = tid >> 4;   // rows 4*ng..4*ng+3
  int cg = tid & 15;   // cols 8*cg..8*cg+7 (all within head cg>>2)
  float acc[4][8];
#pragma unroll
  for (int i = 0; i < 4; ++i)
#pragma unroll
    for (int j = 0; j < 8; ++j) acc[i][j] = 0.f;

  for (int kk = 0; kk < 4; ++kk) {
    __syncthreads();
#pragma unroll
    for (int j = 0; j < 4; ++j) {
      int idx4 = tid + j * 256;
      int r = idx4 >> 5;
      int c4 = idx4 & 31;
      *(float4*)&ws[r * 128 + c4 * 4] = *(const float4*)&W[(kk * 32 + r) * F + c4 * 4];
    }
    __syncthreads();
#pragma unroll
    for (int k = 0; k < 32; ++k) {
      float xv[4];
#pragma unroll
      for (int i = 0; i < 4; ++i) xv[i] = xs[(4 * ng + i) * 132 + kk * 32 + k];
      float4 w0 = *(float4*)&ws[k * 128 + cg * 8];
      float4 w1 = *(float4*)&ws[k * 128 + cg * 8 + 4];
      float wv[8] = {w0.x, w0.y, w0.z, w0.w, w1.x, w1.y, w1.z, w1.w};
#pragma unroll
      for (int i = 0; i < 4; ++i)
#pragma unroll
        for (int j = 0; j < 8; ++j) acc[i][j] += xv[i] * wv[j];
    }
  }

  // --- epilogue 1: bf16 pack + store (16B per row-chunk) ---
#pragma unroll
  for (int i = 0; i < 4; ++i) {
    int r = n0 + 4 * ng + i;
    if (r < N) {
      uint4 pk;
      pk.x = (unsigned)f2bf(acc[i][0]) | ((unsigned)f2bf(acc[i][1]) << 16);
      pk.y = (unsigned)f2bf(acc[i][2]) | ((unsigned)f2bf(acc[i][3]) << 16);
      pk.z = (unsigned)f2bf(acc[i][4]) | ((unsigned)f2bf(acc[i][5]) << 16);
      pk.w = (unsigned)f2bf(acc[i][6]) | ((unsigned)f2bf(acc[i][7]) << 16);
      *(uint4*)&hb[(long)r * F + cg * 8] = pk;
    }
  }

  // --- epilogue 2: el/er via 4-lane shfl_xor reduce ---
  float pl[4], pr[4];
#pragma unroll
  for (int i = 0; i < 4; ++i) { pl[i] = 0.f; pr[i] = 0.f; }
#pragma unroll
  for (int j = 0; j < 8; ++j) {
    float a = alf[cg * 8 + j];
    float b = arf[cg * 8 + j];
#pragma unroll
    for (int i = 0; i < 4; ++i) { pl[i] += acc[i][j] * a; pr[i] += acc[i][j] * b; }
  }
#pragma unroll
  for (int i = 0; i < 4; ++i) {
    pl[i] += __shfl_xor(pl[i], 1); pl[i] += __shfl_xor(pl[i], 2);
    pr[i] += __shfl_xor(pr[i], 1); pr[i] += __shfl_xor(pr[i], 2);
  }
  if ((cg & 3) == 0) {
    int hd = cg >> 2;
#pragma unroll
    for (int i = 0; i < 4; ++i) {
      int r = n0 + 4 * ng + i;
      if (r < N) { el[r * 4 + hd] = pl[i]; er[r * 4 + hd] = pr[i]; }
    }
  }
}

// ---------------- fused edge-softmax + aggregation + bias + ELU ----------------
// One wave per dst; lane owns feats {2l,2l+1} (head = l>>4). Per 16-edge
// sub-batch the 64 lanes compute all 16x4 (edge,head) weights in parallel
// (1 el-gather + 1 expf per lane), removing the gather->exp dependency from
// the serial loop. Serial body: readlane (SGPR src) + bpermute(w) + saddr
// dword gather + 2 FMA, 2-edge unrolled; tail edges get w=0 (no branches).
__global__ __launch_bounds__(256) void agg_k(const int* __restrict__ rp,
                                             const int* __restrict__ csr_src,
                                             const float* __restrict__ el,
                                             const float* __restrict__ er,
                                             const unsigned short* __restrict__ hb,
                                             const float* __restrict__ bias,
                                             float* __restrict__ out, int N) {
  int d = (blockIdx.x * blockDim.x + threadIdx.x) >> 6;
  int lane = threadIdx.x & 63;
  if (d >= N) return;
  int hd = lane >> 4;          // head of this lane's features AND prologue weights
  int lane48 = lane & 48;      // (lane>>4)*16: base lane of this head's weight row
  float erd = er[d * 4 + hd];
  int i0 = rp[d], i1 = rp[d + 1];

  float a0x = 0.f, a0y = 0.f, a1x = 0.f, a1y = 0.f, asum = 0.f;
  for (int base = i0; base < i1; base += 64) {
    int cnt = i1 - base; if (cnt > 64) cnt = 64;
    int sv = 0;
    if (lane < cnt) sv = __builtin_nontemporal_load(&csr_src[base + lane]);
#pragma unroll 4
    for (int sub = 0; sub < 4; ++sub) {
      int sb = sub * 16;
      if (sb >= cnt) break;
      // weights for edges sb..sb+15, head hd (lane computes edge sb+(lane&15))
      int idx = sb + (lane & 15);
      int se = __shfl(sv, idx);
      float e = el[(unsigned)se * 4u + hd] + erd;
      e = e > 0.f ? e : 0.2f * e;           // LeakyReLU(0.2)
      float w = __expf(e);                   // max-subtract unneeded: e ~ N(0,2)
      if (idx >= cnt) w = 0.f;               // tail edges contribute nothing
      int ne = cnt - sb; if (ne > 16) ne = 16;
      for (int j = 0; j < ne; j += 2) {
        int s0 = __builtin_amdgcn_readlane(sv, sb + j);       // SGPR: saddr gather
        int s1 = __builtin_amdgcn_readlane(sv, sb + j + 1);   // (j+1 w==0 if OOB)
        float w0 = __shfl(w, lane48 + j);
        float w1 = __shfl(w, lane48 + j + 1);
        unsigned h0 = *(const unsigned*)(hb + (unsigned)s0 * 128u + (unsigned)lane * 2u);
        unsigned h1 = *(const unsigned*)(hb + (unsigned)s1 * 128u + (unsigned)lane * 2u);
        a0x += w0 * __uint_as_float(h0 << 16);
        a0y += w0 * __uint_as_float(h0 & 0xffff0000u);
        a1x += w1 * __uint_as_float(h1 << 16);
        a1y += w1 * __uint_as_float(h1 & 0xffff0000u);
        asum += w0 + w1;
      }
    }
  }
  float ax = a0x + a1x, ay = a0y + a1y;
  float inv = 1.f / fmaxf(asum, 1e-9f);
  float ox = ax * inv + bias[2 * lane];
  float oy = ay * inv + bias[2 * lane + 1];
  ox = ox > 0.f ? ox : (__expf(ox) - 1.f);  // ELU
  oy = oy > 0.f ? oy : (__expf(oy) - 1.f);
  *(float2*)&out[(size_t)d * F + 2 * lane] = make_float2(ox, oy);
}

extern "C" void kernel_launch(void* const* d_in, const int* in_sizes, int n_in,
                              void* d_out, int out_size, void* d_ws, size_t ws_size,
                              hipStream_t stream) {
  const float* feat = (const float*)d_in[0];
  const int*   src  = (const int*)d_in[1];
  const int*   dst  = (const int*)d_in[2];
  const float* W1   = (const float*)d_in[3];
  const float* al1  = (const float*)d_in[4];
  const float* ar1  = (const float*)d_in[5];
  const float* b1   = (const float*)d_in[6];
  const float* W2   = (const float*)d_in[7];
  const float* al2  = (const float*)d_in[8];
  const float* ar2  = (const float*)d_in[9];
  const float* b2   = (const float*)d_in[10];
  float* out = (float*)d_out;
  int N = in_sizes[0] / F;
  int E = in_sizes[1];

  // workspace layout (~18 MB)
  char* ws = (char*)d_ws;
  auto align256 = [](size_t x) { return (x + 255) & ~(size_t)255; };
  int* rp      = (int*)ws; ws += align256((size_t)(N + 1) * 4);
  int* deg     = (int*)ws; ws += align256((size_t)N * 4);        // becomes cursor
  int* bsum    = (int*)ws; ws += 1024;
  int* csr_src = (int*)ws; ws += align256((size_t)E * 4);
  float* el    = (float*)ws; ws += align256((size_t)N * HEADS * 4);
  float* er    = (float*)ws; ws += align256((size_t)N * HEADS * 4);
  unsigned short* hb = (unsigned short*)ws; ws += align256((size_t)N * F * 2);

  int nbScan = (N + 1023) / 1024;   // 49 <= 64

  // CSR build (graph static but ws is re-poisoned every call — rebuild)
  hipMemsetAsync(deg, 0, (size_t)N * 4, stream);
  hist_k<<<(E + 255) / 256, 256, 0, stream>>>(dst, deg, E);
  block_sum_k<<<nbScan, 256, 0, stream>>>(deg, bsum, N);
  scan_small_k<<<1, 64, 0, stream>>>(bsum, nbScan);
  scan_final_k<<<nbScan, 256, 0, stream>>>(deg, bsum, rp, N, E);
  scatter_k<<<(E + 255) / 256, 256, 0, stream>>>(src, dst, deg, csr_src, E);

  int gemmBlocks = (N + 63) / 64;
  int aggBlocks  = (N + 3) / 4;   // 4 waves / block

  // layer 1: out <- elu(GAT(feat))
  gemm_fused_k<<<gemmBlocks, 256, 0, stream>>>(feat, W1, al1, ar1, hb, el, er, N);
  agg_k<<<aggBlocks, 256, 0, stream>>>(rp, csr_src, el, er, hb, b1, out, N);

  // layer 2: out <- elu(GAT(out))
  gemm_fused_k<<<gemmBlocks, 256, 0, stream>>>(out, W2, al2, ar2, hb, el, er, N);
  agg_k<<<aggBlocks, 256, 0, stream>>>(rp, csr_src, el, er, hb, b2, out, N);
}

// Round 6
// 302.363 us; speedup vs baseline: 1.5047x; 1.1832x over previous
//
#include <hip/hip_runtime.h>

#define F 128      // IN_FEATS == HEADS*HID == 128 (both layers)
#define HEADS 4
#define HID 32
#define LS 136     // LDS row stride in bf16 elements (272 B: 16B-aligned, breaks bank collisions)

typedef __attribute__((ext_vector_type(8))) short short8;   // 8 bf16 = 4 VGPRs
typedef __attribute__((ext_vector_type(4))) float f32x4;

// RNE float -> bf16 bits
static __device__ __forceinline__ unsigned short f2bf(float f) {
  unsigned u = __float_as_uint(f);
  unsigned r = (u + 0x7fffu + ((u >> 16) & 1u)) >> 16;
  return (unsigned short)r;
}
static __device__ __forceinline__ float bf2f(unsigned short h) {
  return __uint_as_float(((unsigned)h) << 16);
}

// ---------------- CSR build (by dst) ----------------
__global__ void hist_k(const int* __restrict__ dst, int* __restrict__ deg, int E) {
  int i = blockIdx.x * blockDim.x + threadIdx.x;
  if (i < E) atomicAdd(&deg[dst[i]], 1);
}

__global__ void block_sum_k(const int* __restrict__ deg, int* __restrict__ bsum, int N) {
  __shared__ int sh[256];
  int t = threadIdx.x;
  int base = blockIdx.x * 1024 + t * 4;
  int s = 0;
#pragma unroll
  for (int m = 0; m < 4; ++m) { int idx = base + m; if (idx < N) s += deg[idx]; }
  sh[t] = s; __syncthreads();
  for (int off = 128; off > 0; off >>= 1) {
    if (t < off) sh[t] += sh[t + off];
    __syncthreads();
  }
  if (t == 0) bsum[blockIdx.x] = sh[0];
}

// exclusive scan of nb<=64 block sums, one wave
__global__ void scan_small_k(int* bsum, int nb) {
  int t = threadIdx.x;
  int v = (t < nb) ? bsum[t] : 0;
  int orig = v;
  for (int off = 1; off < 64; off <<= 1) {
    int u = __shfl_up(v, off);
    if (t >= off) v += u;
  }
  if (t < nb) bsum[t] = v - orig;  // exclusive
}

// exclusive scan of deg -> rp; also writes cursor copy (in-place into deg)
__global__ void scan_final_k(int* __restrict__ deg, const int* __restrict__ bsum,
                             int* __restrict__ rp, int N, int E) {
  __shared__ int sh[256];
  int t = threadIdx.x, b = blockIdx.x;
  int base = b * 1024 + t * 4;
  int v[4]; int ts = 0;
#pragma unroll
  for (int m = 0; m < 4; ++m) { v[m] = (base + m < N) ? deg[base + m] : 0; ts += v[m]; }
  sh[t] = ts; __syncthreads();
  for (int off = 1; off < 256; off <<= 1) {
    int x = (t >= off) ? sh[t - off] : 0;
    __syncthreads();
    sh[t] += x;
    __syncthreads();
  }
  int p = bsum[b] + sh[t] - ts;
#pragma unroll
  for (int m = 0; m < 4; ++m) {
    int idx = base + m;
    if (idx < N) { rp[idx] = p; deg[idx] = p; }
    p += v[m];
  }
  if (b == 0 && t == 0) rp[N] = E;
}

__global__ void scatter_k(const int* __restrict__ src, const int* __restrict__ dst,
                          int* __restrict__ cursor, int* __restrict__ csr_src, int E) {
  int i = blockIdx.x * blockDim.x + threadIdx.x;
  if (i < E) {
    int pos = atomicAdd(&cursor[dst[i]], 1);
    csr_src[pos] = src[i];
  }
}

// ---------------- W transpose + bf16 (both layers, one dispatch) -------------
// WT[n][k] = bf16(W[k][n]); writes coalesced (consecutive k), reads L2-cached.
__global__ void wt_k(const float* __restrict__ W1, const float* __restrict__ W2,
                     unsigned short* __restrict__ WT1, unsigned short* __restrict__ WT2) {
  int gid = blockIdx.x * 256 + threadIdx.x;   // 32768 total
  int wsel = gid >> 14;
  int idx = gid & 16383;
  int n = idx >> 7, k = idx & 127;
  const float* W = wsel ? W2 : W1;
  unsigned short* WT = wsel ? WT2 : WT1;
  WT[n * 128 + k] = f2bf(W[k * 128 + n]);
}

// ---------------- MFMA GEMM + attention logits + bf16 pack -------------------
// H[64-strip,128] = X[64,128] @ W[128,128], bf16 inputs, fp32 MFMA accum.
// Wave w computes rows 16w..16w+15 as 8 n-tiles of v_mfma_f32_16x16x32_bf16.
// A-frag: A[m=lane&15][k=quad*8+j] from xs; B-frag: B[k=quad*8+j][n=lane&15]
// from wt_s (pre-transposed W). C/D: col=lane&15, row=quad*4+reg.
// Epilogue bounces H through LDS (reusing xs) for coalesced uint4 bf16 stores
// and per-(row,head) el/er dot products.
__global__ __launch_bounds__(256) void gemm_mfma_k(const float* __restrict__ X,
                                                   const unsigned short* __restrict__ WT,
                                                   const float* __restrict__ alf,
                                                   const float* __restrict__ arf,
                                                   unsigned short* __restrict__ hb,
                                                   float* __restrict__ el,
                                                   float* __restrict__ er, int N) {
  __shared__ unsigned short wt_s[128 * LS];  // 34.0 KB
  __shared__ unsigned short xs[64 * LS];     // 17.0 KB (reused for H in epilogue)
  int tid = threadIdx.x;
  int n0 = blockIdx.x * 64;

  // stage WT (bf16, already transposed): 128 rows x 16 x 16B chunks = 2048
#pragma unroll
  for (int j = 0; j < 8; ++j) {
    int c = tid + 256 * j;          // 0..2047
    int n = c >> 4, seg = c & 15;
    *(uint4*)&wt_s[n * LS + seg * 8] = *(const uint4*)&WT[n * 128 + seg * 8];
  }
  // stage X strip: fp32 -> bf16, 64 rows x 32 float4 chunks = 2048
#pragma unroll
  for (int j = 0; j < 8; ++j) {
    int c = tid + 256 * j;          // 0..2047
    int r = c >> 5, c4 = c & 31;
    float4 v = make_float4(0.f, 0.f, 0.f, 0.f);
    if (n0 + r < N) v = *(const float4*)&X[(long)(n0 + r) * F + c4 * 4];
    unsigned lo = (unsigned)f2bf(v.x) | ((unsigned)f2bf(v.y) << 16);
    unsigned hi = (unsigned)f2bf(v.z) | ((unsigned)f2bf(v.w) << 16);
    *(uint2*)&xs[r * LS + c4 * 4] = make_uint2(lo, hi);
  }
  __syncthreads();

  int w = tid >> 6, lane = tid & 63;
  int l15 = lane & 15, quad = lane >> 4;
  f32x4 acc[8];
#pragma unroll
  for (int nt = 0; nt < 8; ++nt) acc[nt] = (f32x4){0.f, 0.f, 0.f, 0.f};

  const unsigned short* arow = &xs[(16 * w + l15) * LS + quad * 8];
#pragma unroll
  for (int kk = 0; kk < 4; ++kk) {
    short8 a = *(const short8*)(arow + kk * 32);
#pragma unroll
    for (int nt = 0; nt < 8; ++nt) {
      short8 b = *(const short8*)&wt_s[(nt * 16 + l15) * LS + kk * 32 + quad * 8];
      acc[nt] = __builtin_amdgcn_mfma_f32_16x16x32_bf16(a, b, acc[nt], 0, 0, 0);
    }
  }

  // H -> LDS (reuse xs; all A-frag reads done)
  __syncthreads();
#pragma unroll
  for (int nt = 0; nt < 8; ++nt)
#pragma unroll
    for (int r = 0; r < 4; ++r)
      xs[(16 * w + quad * 4 + r) * LS + nt * 16 + l15] = f2bf(acc[nt][r]);
  __syncthreads();

  // coalesced bf16 stores: 64 rows x 16 x 16B chunks = 1024
#pragma unroll
  for (int j = 0; j < 4; ++j) {
    int c = tid + 256 * j;          // 0..1023
    int r = c >> 4, seg = c & 15;
    if (n0 + r < N)
      *(uint4*)&hb[(long)(n0 + r) * F + seg * 8] = *(uint4*)&xs[r * LS + seg * 8];
  }
  // el/er: thread = (row, head)
  {
    int r = tid >> 2, hd = tid & 3;
    const unsigned short* base = &xs[r * LS + hd * HID];
    float sl = 0.f, sr = 0.f;
#pragma unroll
    for (int d = 0; d < HID; ++d) {
      float hv = bf2f(base[d]);
      sl += hv * alf[hd * HID + d];
      sr += hv * arf[hd * HID + d];
    }
    if (n0 + r < N) { el[(n0 + r) * 4 + hd] = sl; er[(n0 + r) * 4 + hd] = sr; }
  }
}

// ---------------- fused edge-softmax + aggregation + bias + ELU ----------------
// One wave per dst; lane owns feats {2l,2l+1} (head = l>>4). Per 16-edge
// sub-batch the 64 lanes compute all 16x4 (edge,head) weights in parallel.
// Serial body: 4 edges in flight (readlane SGPR src -> saddr dword gather),
// tail edges get w=0 (no branches).
__global__ __launch_bounds__(256) void agg_k(const int* __restrict__ rp,
                                             const int* __restrict__ csr_src,
                                             const float* __restrict__ el,
                                             const float* __restrict__ er,
                                             const unsigned short* __restrict__ hb,
                                             const float* __restrict__ bias,
                                             float* __restrict__ out, int N) {
  int d = (blockIdx.x * blockDim.x + threadIdx.x) >> 6;
  int lane = threadIdx.x & 63;
  if (d >= N) return;
  int hd = lane >> 4;          // head of this lane's features AND prologue weights
  int lane48 = lane & 48;      // (lane>>4)*16: base lane of this head's weight row
  float erd = er[d * 4 + hd];
  int i0 = rp[d], i1 = rp[d + 1];

  float a0x = 0.f, a0y = 0.f, a1x = 0.f, a1y = 0.f;
  float a2x = 0.f, a2y = 0.f, a3x = 0.f, a3y = 0.f;
  float asum = 0.f;
  for (int base = i0; base < i1; base += 64) {
    int cnt = i1 - base; if (cnt > 64) cnt = 64;
    int sv = 0;
    if (lane < cnt) sv = __builtin_nontemporal_load(&csr_src[base + lane]);
#pragma unroll 4
    for (int sub = 0; sub < 4; ++sub) {
      int sb = sub * 16;
      if (sb >= cnt) break;
      // weights for edges sb..sb+15, head hd (lane computes edge sb+(lane&15))
      int idx = sb + (lane & 15);
      int se = __shfl(sv, idx);
      float e = el[(unsigned)se * 4u + hd] + erd;
      e = e > 0.f ? e : 0.2f * e;           // LeakyReLU(0.2)
      float w = __expf(e);                   // max-subtract unneeded: e ~ N(0,2)
      if (idx >= cnt) w = 0.f;               // tail edges contribute nothing
      int ne = cnt - sb; if (ne > 16) ne = 16;
      for (int j = 0; j < ne; j += 4) {      // 4 gathers in flight
        int s0 = __builtin_amdgcn_readlane(sv, sb + j);
        int s1 = __builtin_amdgcn_readlane(sv, sb + j + 1);
        int s2 = __builtin_amdgcn_readlane(sv, sb + j + 2);
        int s3 = __builtin_amdgcn_readlane(sv, sb + j + 3);
        float w0 = __shfl(w, lane48 + j);
        float w1 = __shfl(w, lane48 + j + 1);
        float w2 = __shfl(w, lane48 + j + 2);
        float w3 = __shfl(w, lane48 + j + 3);
        unsigned h0 = *(const unsigned*)(hb + (unsigned)s0 * 128u + (unsigned)lane * 2u);
        unsigned h1 = *(const unsigned*)(hb + (unsigned)s1 * 128u + (unsigned)lane * 2u);
        unsigned h2 = *(const unsigned*)(hb + (unsigned)s2 * 128u + (unsigned)lane * 2u);
        unsigned h3 = *(const unsigned*)(hb + (unsigned)s3 * 128u + (unsigned)lane * 2u);
        a0x += w0 * __uint_as_float(h0 << 16);
        a0y += w0 * __uint_as_float(h0 & 0xffff0000u);
        a1x += w1 * __uint_as_float(h1 << 16);
        a1y += w1 * __uint_as_float(h1 & 0xffff0000u);
        a2x += w2 * __uint_as_float(h2 << 16);
        a2y += w2 * __uint_as_float(h2 & 0xffff0000u);
        a3x += w3 * __uint_as_float(h3 << 16);
        a3y += w3 * __uint_as_float(h3 & 0xffff0000u);
        asum += (w0 + w1) + (w2 + w3);
      }
    }
  }
  float ax = (a0x + a1x) + (a2x + a3x);
  float ay = (a0y + a1y) + (a2y + a3y);
  float inv = 1.f / fmaxf(asum, 1e-9f);
  float ox = ax * inv + bias[2 * lane];
  float oy = ay * inv + bias[2 * lane + 1];
  ox = ox > 0.f ? ox : (__expf(ox) - 1.f);  // ELU
  oy = oy > 0.f ? oy : (__expf(oy) - 1.f);
  *(float2*)&out[(size_t)d * F + 2 * lane] = make_float2(ox, oy);
}

extern "C" void kernel_launch(void* const* d_in, const int* in_sizes, int n_in,
                              void* d_out, int out_size, void* d_ws, size_t ws_size,
                              hipStream_t stream) {
  const float* feat = (const float*)d_in[0];
  const int*   src  = (const int*)d_in[1];
  const int*   dst  = (const int*)d_in[2];
  const float* W1   = (const float*)d_in[3];
  const float* al1  = (const float*)d_in[4];
  const float* ar1  = (const float*)d_in[5];
  const float* b1   = (const float*)d_in[6];
  const float* W2   = (const float*)d_in[7];
  const float* al2  = (const float*)d_in[8];
  const float* ar2  = (const float*)d_in[9];
  const float* b2   = (const float*)d_in[10];
  float* out = (float*)d_out;
  int N = in_sizes[0] / F;
  int E = in_sizes[1];

  // workspace layout (~18 MB)
  char* ws = (char*)d_ws;
  auto align256 = [](size_t x) { return (x + 255) & ~(size_t)255; };
  int* rp      = (int*)ws; ws += align256((size_t)(N + 1) * 4);
  int* deg     = (int*)ws; ws += align256((size_t)N * 4);        // becomes cursor
  int* bsum    = (int*)ws; ws += 1024;
  int* csr_src = (int*)ws; ws += align256((size_t)E * 4);
  float* el    = (float*)ws; ws += align256((size_t)N * HEADS * 4);
  float* er    = (float*)ws; ws += align256((size_t)N * HEADS * 4);
  unsigned short* hb  = (unsigned short*)ws; ws += align256((size_t)N * F * 2);
  unsigned short* WT1 = (unsigned short*)ws; ws += align256((size_t)F * F * 2);
  unsigned short* WT2 = (unsigned short*)ws; ws += align256((size_t)F * F * 2);

  int nbScan = (N + 1023) / 1024;   // 49 <= 64

  // CSR build (graph static but ws is re-poisoned every call — rebuild)
  hipMemsetAsync(deg, 0, (size_t)N * 4, stream);
  hist_k<<<(E + 255) / 256, 256, 0, stream>>>(dst, deg, E);
  block_sum_k<<<nbScan, 256, 0, stream>>>(deg, bsum, N);
  scan_small_k<<<1, 64, 0, stream>>>(bsum, nbScan);
  scan_final_k<<<nbScan, 256, 0, stream>>>(deg, bsum, rp, N, E);
  scatter_k<<<(E + 255) / 256, 256, 0, stream>>>(src, dst, deg, csr_src, E);
  wt_k<<<128, 256, 0, stream>>>(W1, W2, WT1, WT2);

  int gemmBlocks = (N + 63) / 64;
  int aggBlocks  = (N + 3) / 4;   // 4 waves / block

  // layer 1: out <- elu(GAT(feat))
  gemm_mfma_k<<<gemmBlocks, 256, 0, stream>>>(feat, WT1, al1, ar1, hb, el, er, N);
  agg_k<<<aggBlocks, 256, 0, stream>>>(rp, csr_src, el, er, hb, b1, out, N);

  // layer 2: out <- elu(GAT(out))
  gemm_mfma_k<<<gemmBlocks, 256, 0, stream>>>(out, WT2, al2, ar2, hb, el, er, N);
  agg_k<<<aggBlocks, 256, 0, stream>>>(rp, csr_src, el, er, hb, b2, out, N);
}